// Round 1
// 3910.376 us; speedup vs baseline: 1.1619x; 1.1619x over previous
//
#include <hip/hip_runtime.h>
#include <math.h>

typedef unsigned short u16;
typedef short short8 __attribute__((ext_vector_type(8)));
typedef float floatx4 __attribute__((ext_vector_type(4)));
typedef u16 u16x4 __attribute__((ext_vector_type(4)));

#define L_ 6
#define D_ 1024
#define DFF_ 4096
#define V_ 32000
#define T_ 1024
#define B_ 2
#define H_ 16
#define M_ (B_*T_)

__device__ __forceinline__ float b2f(u16 v){ union{unsigned u; float f;} x; x.u = ((unsigned)v)<<16; return x.f; }
__device__ __forceinline__ u16 f2bf(float f){ union{float f; unsigned u;} x; x.f=f; unsigned r = x.u + 0x7fffu + ((x.u>>16)&1u); return (u16)(r>>16); }

__device__ __forceinline__ void gload16(const u16* g, u16* l){
  __builtin_amdgcn_global_load_lds((const __attribute__((address_space(1))) void*)g,
                                   (__attribute__((address_space(3))) void*)l, 16, 0, 0);
}

// ---------------- embedding: x = tok_emb[idx] + pos_emb (all fp32) ----------------
__global__ __launch_bounds__(256) void embed_kernel(const int* __restrict__ idx,
    const float* __restrict__ tok, const float* __restrict__ pos, float* __restrict__ x)
{
  int m = blockIdx.x;
  int t = m & (T_-1);
  int id = idx[m];
  int d = threadIdx.x*4;
  floatx4 tv = *(const floatx4*)(tok + (size_t)id*D_ + d);
  floatx4 pv = *(const floatx4*)(pos + (size_t)t*D_ + d);
  floatx4 r = tv + pv;
  *(floatx4*)(x + (size_t)m*D_ + d) = r;
}

// ---------------- fp32 -> bf16 weight conversion (2048 elems / block) ----------------
__global__ __launch_bounds__(256) void cvt_kernel(const float* __restrict__ src, u16* __restrict__ dst)
{
  size_t i = ((size_t)blockIdx.x*256 + threadIdx.x)*8;
  floatx4 a = *(const floatx4*)(src + i);
  floatx4 b = *(const floatx4*)(src + i + 4);
  short8 o;
  #pragma unroll
  for (int j=0;j<4;j++){ o[j] = (short)f2bf(a[j]); o[4+j] = (short)f2bf(b[j]); }
  *(short8*)(dst + i) = o;
}

// ---------------- layernorm: fp32 in, bf16 out ----------------
__global__ __launch_bounds__(256) void ln_kernel(const float* __restrict__ x,
    const float* __restrict__ w, const float* __restrict__ b, u16* __restrict__ out)
{
  int row = blockIdx.x, tid = threadIdx.x;
  const float* xr = x + (size_t)row*D_;
  floatx4 v = *(const floatx4*)(xr + tid*4);
  float s  = v[0]+v[1]+v[2]+v[3];
  float sq = v[0]*v[0]+v[1]*v[1]+v[2]*v[2]+v[3]*v[3];
  #pragma unroll
  for (int m=32;m>0;m>>=1){ s += __shfl_xor(s,m); sq += __shfl_xor(sq,m); }
  __shared__ float red[8];
  if ((tid&63)==0){ red[tid>>6]=s; red[4+(tid>>6)]=sq; }
  __syncthreads();
  float st  = red[0]+red[1]+red[2]+red[3];
  float sqt = red[4]+red[5]+red[6]+red[7];
  float mu = st*(1.0f/D_);
  float rs = rsqrtf(sqt*(1.0f/D_) - mu*mu + 1e-5f);
  floatx4 wv = *(const floatx4*)(w + tid*4);
  floatx4 bv = *(const floatx4*)(b + tid*4);
  u16x4 o;
  #pragma unroll
  for(int j=0;j<4;j++) o[j] = f2bf((v[j]-mu)*rs*wv[j] + bv[j]);
  *(u16x4*)(out + (size_t)row*D_ + tid*4) = o;
}

// ---------------- bf16 MFMA GEMM (m97 structure): C[M,N] = A[M,K] @ W[N,K]^T ----------------
// A: bf16. Bw: bf16 (pre-converted). Linear LDS tiles, global_load_lds width-16 staging.
// mode 1: store fp32   mode 2: gelu -> bf16   mode 3: fp32 C += acc
#define BM 128
#define BN 128
#define BK 32

__global__ __launch_bounds__(256) void gemm_bf16(const u16* __restrict__ A,
    const u16* __restrict__ Bw, void* __restrict__ Cp,
    int M, int N, int K, int mode)
{
  __shared__ __align__(16) u16 As[BM*BK];
  __shared__ __align__(16) u16 Bs[BN*BK];
  int tid = threadIdx.x;
  int n0 = blockIdx.x*BN, m0 = blockIdx.y*BM;
  int w = tid>>6, lane = tid&63, quad = lane>>4, r16 = lane&15;
  int wm = (w>>1)*64, wn = (w&1)*64;

  // staging: 512 chunks of 16B per tile; wave w owns chunks [w*128, w*128+128)
  // chunk c -> row c>>2, elem col (c&3)*8 ; LDS linear elem offset = c*8
  int c0 = w*128 + lane;
  int c1 = c0 + 64;
  const u16* ga0 = A  + (size_t)(m0 + (c0>>2))*K + (c0&3)*8;
  const u16* ga1 = A  + (size_t)(m0 + (c1>>2))*K + (c1&3)*8;
  const u16* gb0 = Bw + (size_t)(n0 + (c0>>2))*K + (c0&3)*8;
  const u16* gb1 = Bw + (size_t)(n0 + (c1>>2))*K + (c1&3)*8;
  u16* la0 = As + (size_t)(w*128    )*8;
  u16* la1 = As + (size_t)(w*128+ 64)*8;
  u16* lb0 = Bs + (size_t)(w*128    )*8;
  u16* lb1 = Bs + (size_t)(w*128+ 64)*8;

  floatx4 acc[4][4];
  #pragma unroll
  for(int i=0;i<4;i++)
    #pragma unroll
    for(int j=0;j<4;j++) acc[i][j] = (floatx4)0.0f;

  for (int k0=0; k0<K; k0+=BK){
    __syncthreads();                 // prev tile fully consumed
    gload16(ga0 + k0, la0);
    gload16(ga1 + k0, la1);
    gload16(gb0 + k0, lb0);
    gload16(gb1 + k0, lb1);
    __syncthreads();                 // drains vmcnt(0): tile visible
    short8 af[4], bfr[4];
    #pragma unroll
    for (int i=0;i<4;i++){
      af[i]  = *(const short8*)(As + (wm + i*16 + r16)*BK + quad*8);
      bfr[i] = *(const short8*)(Bs + (wn + i*16 + r16)*BK + quad*8);
    }
    #pragma unroll
    for (int mi=0;mi<4;mi++)
      #pragma unroll
      for (int ni=0;ni<4;ni++)
        acc[mi][ni] = __builtin_amdgcn_mfma_f32_16x16x32_bf16(af[mi], bfr[ni], acc[mi][ni], 0,0,0);
  }

  #pragma unroll
  for (int mi=0;mi<4;mi++){
    #pragma unroll
    for (int ni=0;ni<4;ni++){
      #pragma unroll
      for (int r=0;r<4;r++){
        int m = m0 + wm + mi*16 + quad*4 + r;   // C/D: row = quad*4+reg
        int n = n0 + wn + ni*16 + r16;          //      col = lane&15
        float v = acc[mi][ni][r];
        size_t off = (size_t)m*N + n;
        if (mode==1)      ((float*)Cp)[off] = v;
        else if (mode==2) ((u16*)Cp)[off]   = f2bf(0.5f*v*(1.0f + erff(v*0.70710678118654752f)));
        else              ((float*)Cp)[off] += v;
      }
    }
  }
}

// ---------------- causal attention, online softmax, wave-per-qrow ----------------
// qkv fp32 [M, 3D] layout [q|k|v][h][hd]; out bf16 [M, D]
__global__ __launch_bounds__(256) void attn_kernel(const float* __restrict__ qkv,
    u16* __restrict__ out)
{
  __shared__ float Ks[64*65];
  __shared__ float Vs[64*65];
  __shared__ float qsh[4][64];
  __shared__ float ps[4][64];
  int bh = blockIdx.x, b = bh>>4, h = bh&15;
  int w = threadIdx.x>>6, lane = threadIdx.x&63;
  int q = blockIdx.y*4 + w;
  qsh[w][lane] = qkv[((size_t)(b*T_) + q)*3072 + h*64 + lane];
  float o = 0.f, m_run = -INFINITY, l_run = 0.f;
  int nkb = ((blockIdx.y*4+3)>>6) + 1;
  for (int kb=0; kb<nkb; kb++){
    __syncthreads();   // prev tile fully consumed (and qsh visible on kb=0)
    #pragma unroll
    for (int i=0;i<4;i++){
      int f = i*256 + threadIdx.x;     // 1024 float4 chunks per tile
      int r = f>>4, c = (f&15)*4;
      const float* src = qkv + ((size_t)(b*T_) + kb*64 + r)*3072 + h*64 + c;
      floatx4 kv = *(const floatx4*)(src + D_);
      floatx4 vv = *(const floatx4*)(src + 2*D_);
      int base = r*65 + c;
      #pragma unroll
      for (int j=0;j<4;j++){ Ks[base+j]=kv[j]; Vs[base+j]=vv[j]; }
    }
    __syncthreads();
    int kg = kb*64 + lane;
    float s = 0.f;
    #pragma unroll
    for (int d=0; d<64; d++) s += qsh[w][d]*Ks[lane*65+d];
    s *= 0.125f;
    if (kg > q) s = -INFINITY;
    float mt = s;
    #pragma unroll
    for (int msk=32;msk>0;msk>>=1) mt = fmaxf(mt, __shfl_xor(mt,msk));
    float nm = fmaxf(m_run, mt);
    float alpha = (m_run==-INFINITY) ? 0.f : expf(m_run-nm);
    float p = expf(s-nm);
    float psum = p;
    #pragma unroll
    for (int msk=32;msk>0;msk>>=1) psum += __shfl_xor(psum,msk);
    l_run = l_run*alpha + psum;
    o *= alpha;
    m_run = nm;
    ps[w][lane] = p;
    __syncthreads();   // ps ordering (uniform across waves)
    #pragma unroll 8
    for (int k=0;k<64;k++) o += ps[w][k]*Vs[k*65+lane];
  }
  out[((size_t)(b*T_)+q)*D_ + h*64 + lane] = f2bf(o/l_run);
}

// ---------------- driver ----------------
extern "C" void kernel_launch(void* const* d_in, const int* in_sizes, int n_in,
                              void* d_out, int out_size, void* d_ws, size_t ws_size,
                              hipStream_t stream)
{
  const int*   idx = (const int*)d_in[0];
  const float* tok = (const float*)d_in[1];
  const float* pos = (const float*)d_in[2];
  const float* ln1w = (const float*)d_in[3];
  const float* ln1b = (const float*)d_in[4];
  const float* qkvw = (const float*)d_in[5];
  const float* outw = (const float*)d_in[6];
  const float* ln2w = (const float*)d_in[7];
  const float* ln2b = (const float*)d_in[8];
  const float* f1w  = (const float*)d_in[9];
  const float* f2w  = (const float*)d_in[10];
  const float* lnfw = (const float*)d_in[11];
  const float* lnfb = (const float*)d_in[12];

  char* ws = (char*)d_ws;
  float* x   = (float*)ws;                      // 8 MB   [2048,1024] fp32 residual stream
  u16*  h    = (u16*) (ws + (size_t)( 8<<20));  // 4 MB   [2048,1024] bf16 LN out
  float* qkv = (float*)(ws + (size_t)(12<<20)); // 24 MB  [2048,3072] fp32
  u16*  ao   = (u16*) (ws + (size_t)(36<<20));  // 4 MB   [2048,1024] bf16 attn out
  u16*  ff   = (u16*) (ws + (size_t)(40<<20));  // 16 MB  [2048,4096] bf16 gelu out
  u16*  wb   = (u16*) (ws + (size_t)(56<<20));  // 64 MB  bf16 weight scratch (max: tok_emb 62.5 MiB)
  if (ws_size < ((size_t)120<<20)) return;

  embed_kernel<<<M_, 256, 0, stream>>>(idx, tok, pos, x);
  for (int l=0; l<L_; l++){
    ln_kernel<<<M_, 256, 0, stream>>>(x, ln1w + l*D_, ln1b + l*D_, h);
    cvt_kernel<<<(3*D_*D_)/2048, 256, 0, stream>>>(qkvw + (size_t)l*3*D_*D_, wb);
    gemm_bf16<<<dim3(3*D_/BN, M_/BM), 256, 0, stream>>>(h, wb, qkv, M_, 3*D_, D_, 1);
    attn_kernel<<<dim3(B_*H_, T_/4), 256, 0, stream>>>(qkv, ao);
    cvt_kernel<<<(D_*D_)/2048, 256, 0, stream>>>(outw + (size_t)l*D_*D_, wb);
    gemm_bf16<<<dim3(D_/BN, M_/BM), 256, 0, stream>>>(ao, wb, x, M_, D_, D_, 3);
    ln_kernel<<<M_, 256, 0, stream>>>(x, ln2w + l*D_, ln2b + l*D_, h);
    cvt_kernel<<<(DFF_*D_)/2048, 256, 0, stream>>>(f1w + (size_t)l*DFF_*D_, wb);
    gemm_bf16<<<dim3(DFF_/BN, M_/BM), 256, 0, stream>>>(h, wb, ff, M_, DFF_, D_, 2);
    cvt_kernel<<<(D_*DFF_)/2048, 256, 0, stream>>>(f2w + (size_t)l*D_*DFF_, wb);
    gemm_bf16<<<dim3(D_/BN, M_/BM), 256, 0, stream>>>(ff, wb, x, M_, D_, DFF_, 3);
  }
  ln_kernel<<<M_, 256, 0, stream>>>(x, lnfw, lnfb, h);
  cvt_kernel<<<(V_*D_)/2048, 256, 0, stream>>>(tok, wb);
  gemm_bf16<<<dim3(V_/BN, M_/BM), 256, 0, stream>>>(h, wb, (float*)d_out, M_, V_, D_, 1);
}

// Round 2
// 2502.570 us; speedup vs baseline: 1.8155x; 1.5625x over previous
//
#include <hip/hip_runtime.h>
#include <math.h>

typedef unsigned short u16;
typedef short short8 __attribute__((ext_vector_type(8)));
typedef float floatx4 __attribute__((ext_vector_type(4)));
typedef u16 u16x4 __attribute__((ext_vector_type(4)));

#define L_ 6
#define D_ 1024
#define DFF_ 4096
#define V_ 32000
#define T_ 1024
#define B_ 2
#define H_ 16
#define M_ (B_*T_)

__device__ __forceinline__ float b2f(u16 v){ union{unsigned u; float f;} x; x.u = ((unsigned)v)<<16; return x.f; }
__device__ __forceinline__ u16 f2bf(float f){ union{float f; unsigned u;} x; x.f=f; unsigned r = x.u + 0x7fffu + ((x.u>>16)&1u); return (u16)(r>>16); }

__device__ __forceinline__ void gload16(const u16* g, u16* l){
  __builtin_amdgcn_global_load_lds((const __attribute__((address_space(1))) void*)g,
                                   (__attribute__((address_space(3))) void*)l, 16, 0, 0);
}

// ---------------- embedding: x = tok_emb[idx] + pos_emb (all fp32) ----------------
__global__ __launch_bounds__(256) void embed_kernel(const int* __restrict__ idx,
    const float* __restrict__ tok, const float* __restrict__ pos, float* __restrict__ x)
{
  int m = blockIdx.x;
  int t = m & (T_-1);
  int id = idx[m];
  int d = threadIdx.x*4;
  floatx4 tv = *(const floatx4*)(tok + (size_t)id*D_ + d);
  floatx4 pv = *(const floatx4*)(pos + (size_t)t*D_ + d);
  floatx4 r = tv + pv;
  *(floatx4*)(x + (size_t)m*D_ + d) = r;
}

// ---------------- fp32 -> bf16 weight conversion (2048 elems / block) ----------------
__global__ __launch_bounds__(256) void cvt_kernel(const float* __restrict__ src, u16* __restrict__ dst)
{
  size_t i = ((size_t)blockIdx.x*256 + threadIdx.x)*8;
  floatx4 a = *(const floatx4*)(src + i);
  floatx4 b = *(const floatx4*)(src + i + 4);
  short8 o;
  #pragma unroll
  for (int j=0;j<4;j++){ o[j] = (short)f2bf(a[j]); o[4+j] = (short)f2bf(b[j]); }
  *(short8*)(dst + i) = o;
}

// ---------------- layernorm: fp32 in, bf16 out ----------------
__global__ __launch_bounds__(256) void ln_kernel(const float* __restrict__ x,
    const float* __restrict__ w, const float* __restrict__ b, u16* __restrict__ out)
{
  int row = blockIdx.x, tid = threadIdx.x;
  const float* xr = x + (size_t)row*D_;
  floatx4 v = *(const floatx4*)(xr + tid*4);
  float s  = v[0]+v[1]+v[2]+v[3];
  float sq = v[0]*v[0]+v[1]*v[1]+v[2]*v[2]+v[3]*v[3];
  #pragma unroll
  for (int m=32;m>0;m>>=1){ s += __shfl_xor(s,m); sq += __shfl_xor(sq,m); }
  __shared__ float red[8];
  if ((tid&63)==0){ red[tid>>6]=s; red[4+(tid>>6)]=sq; }
  __syncthreads();
  float st  = red[0]+red[1]+red[2]+red[3];
  float sqt = red[4]+red[5]+red[6]+red[7];
  float mu = st*(1.0f/D_);
  float rs = rsqrtf(sqt*(1.0f/D_) - mu*mu + 1e-5f);
  floatx4 wv = *(const floatx4*)(w + tid*4);
  floatx4 bv = *(const floatx4*)(b + tid*4);
  u16x4 o;
  #pragma unroll
  for(int j=0;j<4;j++) o[j] = f2bf((v[j]-mu)*rs*wv[j] + bv[j]);
  *(u16x4*)(out + (size_t)row*D_ + tid*4) = o;
}

// ---------------- bf16 MFMA GEMM (m97 structure): C[M,N] = A[M,K] @ W[N,K]^T ----------------
// mode 1: fp32 store  mode 2: gelu->bf16  mode 3: fp32 +=  mode 4: bf16 store
#define BM 128
#define BN 128
#define BK 32

__global__ __launch_bounds__(256) void gemm_bf16(const u16* __restrict__ A,
    const u16* __restrict__ Bw, void* __restrict__ Cp,
    int M, int N, int K, int mode)
{
  __shared__ __align__(16) u16 As[BM*BK];
  __shared__ __align__(16) u16 Bs[BN*BK];
  int tid = threadIdx.x;
  int n0 = blockIdx.x*BN, m0 = blockIdx.y*BM;
  int w = tid>>6, lane = tid&63, quad = lane>>4, r16 = lane&15;
  int wm = (w>>1)*64, wn = (w&1)*64;

  int c0 = w*128 + lane;
  int c1 = c0 + 64;
  const u16* ga0 = A  + (size_t)(m0 + (c0>>2))*K + (c0&3)*8;
  const u16* ga1 = A  + (size_t)(m0 + (c1>>2))*K + (c1&3)*8;
  const u16* gb0 = Bw + (size_t)(n0 + (c0>>2))*K + (c0&3)*8;
  const u16* gb1 = Bw + (size_t)(n0 + (c1>>2))*K + (c1&3)*8;
  u16* la0 = As + (size_t)(w*128    )*8;
  u16* la1 = As + (size_t)(w*128+ 64)*8;
  u16* lb0 = Bs + (size_t)(w*128    )*8;
  u16* lb1 = Bs + (size_t)(w*128+ 64)*8;

  floatx4 acc[4][4];
  #pragma unroll
  for(int i=0;i<4;i++)
    #pragma unroll
    for(int j=0;j<4;j++) acc[i][j] = (floatx4)0.0f;

  for (int k0=0; k0<K; k0+=BK){
    __syncthreads();
    gload16(ga0 + k0, la0);
    gload16(ga1 + k0, la1);
    gload16(gb0 + k0, lb0);
    gload16(gb1 + k0, lb1);
    __syncthreads();
    short8 af[4], bfr[4];
    #pragma unroll
    for (int i=0;i<4;i++){
      af[i]  = *(const short8*)(As + (wm + i*16 + r16)*BK + quad*8);
      bfr[i] = *(const short8*)(Bs + (wn + i*16 + r16)*BK + quad*8);
    }
    #pragma unroll
    for (int mi=0;mi<4;mi++)
      #pragma unroll
      for (int ni=0;ni<4;ni++)
        acc[mi][ni] = __builtin_amdgcn_mfma_f32_16x16x32_bf16(af[mi], bfr[ni], acc[mi][ni], 0,0,0);
  }

  #pragma unroll
  for (int mi=0;mi<4;mi++){
    #pragma unroll
    for (int ni=0;ni<4;ni++){
      #pragma unroll
      for (int r=0;r<4;r++){
        int m = m0 + wm + mi*16 + quad*4 + r;
        int n = n0 + wn + ni*16 + r16;
        float v = acc[mi][ni][r];
        size_t off = (size_t)m*N + n;
        if (mode==1)      ((float*)Cp)[off] = v;
        else if (mode==2) ((u16*)Cp)[off]   = f2bf(0.5f*v*(1.0f + erff(v*0.70710678118654752f)));
        else if (mode==4) ((u16*)Cp)[off]   = f2bf(v);
        else              ((float*)Cp)[off] += v;
      }
    }
  }
}

// ---------------- V transpose: qkv bf16 [M][3072] -> Vt bf16 [32 bh][64 d][1024 t] ----------------
__global__ __launch_bounds__(256) void vtrans_kernel(const u16* __restrict__ qkv, u16* __restrict__ Vt)
{
  __shared__ u16 Lt[64*72];
  int bh = blockIdx.x, b = bh>>4, h = bh&15;
  int tt = blockIdx.y;
  int tid = threadIdx.x;
  #pragma unroll
  for (int cc=0; cc<2; cc++){
    int c = tid + cc*256;
    int t = c>>3, dc = (c&7)*8;
    short8 v = *(const short8*)(qkv + ((size_t)(b*T_) + tt*64 + t)*3072 + 2048 + h*64 + dc);
    *(short8*)(Lt + t*72 + dc) = v;
  }
  __syncthreads();
  #pragma unroll
  for (int cc=0; cc<2; cc++){
    int c = tid + cc*256;
    int d = c>>3, tc = (c&7)*8;
    short8 o;
    #pragma unroll
    for (int j=0;j<8;j++) o[j] = (short)Lt[(tc+j)*72 + d];
    *(short8*)(Vt + ((size_t)bh*64 + d)*T_ + tt*64 + tc) = o;
  }
}

// ---------------- MFMA flash attention ----------------
// qkv bf16 [M][3072] ([q|k|v][h][64]); Vt bf16 [32][64][1024]; out bf16 [M][1024]
// block: (bh, y) -> qtile qt (64 q rows), 4 waves x 16 rows. K-tiles of 64.
__global__ __launch_bounds__(256) void attn_mfma(const u16* __restrict__ qkv,
    const u16* __restrict__ Vt, u16* __restrict__ out)
{
  __shared__ __align__(16) u16 Qs[64*72];
  __shared__ __align__(16) u16 Ksh[64*72];
  __shared__ __align__(16) u16 Vts[64*72];
  __shared__ __align__(16) u16 Pls[4][16*72];
  int bh = blockIdx.x, b = bh>>4, h = bh&15;
  int y = blockIdx.y;
  int qt = (y<8) ? y : 23-y;                 // work-balance pairing: qt(y)+qt(y+8)=15
  int tid = threadIdx.x, w = tid>>6, lane = tid&63, quad = lane>>4, r16 = lane&15;

  // stage Q tile (64 rows x 64 d)
  #pragma unroll
  for (int cc=0; cc<2; cc++){
    int c = tid + cc*256;
    int r = c>>3, dc = (c&7)*8;
    short8 v = *(const short8*)(qkv + ((size_t)(b*T_) + qt*64 + r)*3072 + h*64 + dc);
    *(short8*)(Qs + r*72 + dc) = v;
  }
  __syncthreads();
  short8 qf[2];
  qf[0] = *(const short8*)(Qs + (w*16 + r16)*72 + quad*8);
  qf[1] = *(const short8*)(Qs + (w*16 + r16)*72 + quad*8 + 32);

  floatx4 oacc[4];
  #pragma unroll
  for (int i=0;i<4;i++) oacc[i] = (floatx4)0.0f;
  float m_run[4], l_run[4];
  #pragma unroll
  for (int r=0;r<4;r++){ m_run[r] = -INFINITY; l_run[r] = 0.f; }
  int qg = qt*64 + w*16 + quad*4;            // + r

  for (int kb=0; kb<=qt; kb++){
    __syncthreads();                          // prev K/V tile consumed
    #pragma unroll
    for (int cc=0; cc<2; cc++){
      int c = tid + cc*256;
      int r = c>>3, dc = (c&7)*8;
      short8 kv = *(const short8*)(qkv + ((size_t)(b*T_) + kb*64 + r)*3072 + D_ + h*64 + dc);
      *(short8*)(Ksh + r*72 + dc) = kv;
      short8 vv = *(const short8*)(Vt + ((size_t)bh*64 + r)*T_ + kb*64 + dc);
      *(short8*)(Vts + r*72 + dc) = vv;
    }
    __syncthreads();

    // S[16q][64k] = Q @ K^T   (C/D: row q = quad*4+r, col k = nt*16 + r16)
    floatx4 sa[4];
    #pragma unroll
    for (int nt=0;nt<4;nt++) sa[nt] = (floatx4)0.0f;
    #pragma unroll
    for (int nt=0;nt<4;nt++){
      short8 kf0 = *(const short8*)(Ksh + (nt*16 + r16)*72 + quad*8);
      short8 kf1 = *(const short8*)(Ksh + (nt*16 + r16)*72 + quad*8 + 32);
      sa[nt] = __builtin_amdgcn_mfma_f32_16x16x32_bf16(qf[0], kf0, sa[nt], 0,0,0);
      sa[nt] = __builtin_amdgcn_mfma_f32_16x16x32_bf16(qf[1], kf1, sa[nt], 0,0,0);
    }
    bool diag = (kb==qt);
    #pragma unroll
    for (int nt=0;nt<4;nt++)
      #pragma unroll
      for (int r=0;r<4;r++){
        float s = sa[nt][r]*0.125f;
        if (diag && (kb*64 + nt*16 + r16) > (qg + r)) s = -INFINITY;
        sa[nt][r] = s;
      }

    // online softmax in-fragment: row's 64 cols = 4 in-lane accs x 16 quad-lanes
    float mt[4];
    #pragma unroll
    for (int r=0;r<4;r++) mt[r] = fmaxf(fmaxf(sa[0][r],sa[1][r]), fmaxf(sa[2][r],sa[3][r]));
    #pragma unroll
    for (int msk=1; msk<16; msk<<=1)
      #pragma unroll
      for (int r=0;r<4;r++) mt[r] = fmaxf(mt[r], __shfl_xor(mt[r], msk));
    float alpha[4];
    #pragma unroll
    for (int r=0;r<4;r++){
      float nm = fmaxf(m_run[r], mt[r]);
      alpha[r] = __expf(m_run[r]-nm);        // exp(-inf)=0 on first tile
      m_run[r] = nm;
    }
    float psum[4] = {0.f,0.f,0.f,0.f};
    #pragma unroll
    for (int nt=0;nt<4;nt++)
      #pragma unroll
      for (int r=0;r<4;r++){
        float p = __expf(sa[nt][r]-m_run[r]);
        sa[nt][r] = p;
        psum[r] += p;
      }
    #pragma unroll
    for (int msk=1; msk<16; msk<<=1)
      #pragma unroll
      for (int r=0;r<4;r++) psum[r] += __shfl_xor(psum[r], msk);
    #pragma unroll
    for (int r=0;r<4;r++) l_run[r] = l_run[r]*alpha[r] + psum[r];
    #pragma unroll
    for (int nt=0;nt<4;nt++)
      #pragma unroll
      for (int r=0;r<4;r++) oacc[nt][r] *= alpha[r];

    // P -> per-wave LDS (C/D layout in, A-frag layout out). Wave-private: no barrier.
    #pragma unroll
    for (int nt=0;nt<4;nt++)
      #pragma unroll
      for (int r=0;r<4;r++)
        Pls[w][(quad*4+r)*72 + nt*16 + r16] = f2bf(sa[nt][r]);
    short8 pf0 = *(const short8*)(&Pls[w][r16*72 + quad*8]);
    short8 pf1 = *(const short8*)(&Pls[w][r16*72 + quad*8 + 32]);

    // O[16q][64d] += P @ V   (B-frag rows = d from Vt tile)
    #pragma unroll
    for (int nt=0;nt<4;nt++){
      short8 vf0 = *(const short8*)(Vts + (nt*16 + r16)*72 + quad*8);
      short8 vf1 = *(const short8*)(Vts + (nt*16 + r16)*72 + quad*8 + 32);
      oacc[nt] = __builtin_amdgcn_mfma_f32_16x16x32_bf16(pf0, vf0, oacc[nt], 0,0,0);
      oacc[nt] = __builtin_amdgcn_mfma_f32_16x16x32_bf16(pf1, vf1, oacc[nt], 0,0,0);
    }
  }

  float inv[4];
  #pragma unroll
  for (int r=0;r<4;r++) inv[r] = 1.f/l_run[r];
  #pragma unroll
  for (int nt=0;nt<4;nt++)
    #pragma unroll
    for (int r=0;r<4;r++)
      out[((size_t)(b*T_) + qt*64 + w*16 + quad*4 + r)*D_ + h*64 + nt*16 + r16] = f2bf(oacc[nt][r]*inv[r]);
}

// ---------------- driver ----------------
extern "C" void kernel_launch(void* const* d_in, const int* in_sizes, int n_in,
                              void* d_out, int out_size, void* d_ws, size_t ws_size,
                              hipStream_t stream)
{
  const int*   idx = (const int*)d_in[0];
  const float* tok = (const float*)d_in[1];
  const float* pos = (const float*)d_in[2];
  const float* ln1w = (const float*)d_in[3];
  const float* ln1b = (const float*)d_in[4];
  const float* qkvw = (const float*)d_in[5];
  const float* outw = (const float*)d_in[6];
  const float* ln2w = (const float*)d_in[7];
  const float* ln2b = (const float*)d_in[8];
  const float* f1w  = (const float*)d_in[9];
  const float* f2w  = (const float*)d_in[10];
  const float* lnfw = (const float*)d_in[11];
  const float* lnfb = (const float*)d_in[12];

  char* ws = (char*)d_ws;
  float* x   = (float*)ws;                      // 8 MB   [2048,1024] fp32 residual
  u16*  h    = (u16*) (ws + (size_t)( 8<<20));  // 4 MB   [2048,1024] bf16 LN out
  u16*  qkv  = (u16*) (ws + (size_t)(12<<20));  // 12 MB  [2048,3072] bf16
  u16*  ao   = (u16*) (ws + (size_t)(24<<20));  // 4 MB   [2048,1024] bf16 attn out
  u16*  ff   = (u16*) (ws + (size_t)(28<<20));  // 16 MB  [2048,4096] bf16 gelu out
  u16*  vt   = (u16*) (ws + (size_t)(44<<20));  // 4 MB   [32,64,1024] bf16 V^T
  u16*  wb   = (u16*) (ws + (size_t)(48<<20));  // 64 MB  bf16 weight scratch
  if (ws_size < ((size_t)120<<20)) return;

  embed_kernel<<<M_, 256, 0, stream>>>(idx, tok, pos, x);
  for (int l=0; l<L_; l++){
    ln_kernel<<<M_, 256, 0, stream>>>(x, ln1w + l*D_, ln1b + l*D_, h);
    cvt_kernel<<<(3*D_*D_)/2048, 256, 0, stream>>>(qkvw + (size_t)l*3*D_*D_, wb);
    gemm_bf16<<<dim3(3*D_/BN, M_/BM), 256, 0, stream>>>(h, wb, qkv, M_, 3*D_, D_, 4);
    vtrans_kernel<<<dim3(B_*H_, T_/64), 256, 0, stream>>>(qkv, vt);
    attn_mfma<<<dim3(B_*H_, T_/64), 256, 0, stream>>>(qkv, vt, ao);
    cvt_kernel<<<(D_*D_)/2048, 256, 0, stream>>>(outw + (size_t)l*D_*D_, wb);
    gemm_bf16<<<dim3(D_/BN, M_/BM), 256, 0, stream>>>(ao, wb, x, M_, D_, D_, 3);
    ln_kernel<<<M_, 256, 0, stream>>>(x, ln2w + l*D_, ln2b + l*D_, h);
    cvt_kernel<<<(DFF_*D_)/2048, 256, 0, stream>>>(f1w + (size_t)l*DFF_*D_, wb);
    gemm_bf16<<<dim3(DFF_/BN, M_/BM), 256, 0, stream>>>(h, wb, ff, M_, DFF_, D_, 2);
    cvt_kernel<<<(D_*DFF_)/2048, 256, 0, stream>>>(f2w + (size_t)l*D_*DFF_, wb);
    gemm_bf16<<<dim3(D_/BN, M_/BM), 256, 0, stream>>>(ff, wb, x, M_, D_, DFF_, 3);
  }
  ln_kernel<<<M_, 256, 0, stream>>>(x, lnfw, lnfb, h);
  cvt_kernel<<<(V_*D_)/2048, 256, 0, stream>>>(tok, wb);
  gemm_bf16<<<dim3(V_/BN, M_/BM), 256, 0, stream>>>(h, wb, (float*)d_out, M_, V_, D_, 1);
}

// Round 3
// 2348.360 us; speedup vs baseline: 1.9347x; 1.0657x over previous
//
#include <hip/hip_runtime.h>
#include <math.h>

typedef unsigned short u16;
typedef short short8 __attribute__((ext_vector_type(8)));
typedef float floatx4 __attribute__((ext_vector_type(4)));
typedef u16 u16x4 __attribute__((ext_vector_type(4)));

#define L_ 6
#define D_ 1024
#define DFF_ 4096
#define V_ 32000
#define T_ 1024
#define B_ 2
#define H_ 16
#define M_ (B_*T_)

__device__ __forceinline__ float b2f(u16 v){ union{unsigned u; float f;} x; x.u = ((unsigned)v)<<16; return x.f; }
__device__ __forceinline__ u16 f2bf(float f){ union{float f; unsigned u;} x; x.f=f; unsigned r = x.u + 0x7fffu + ((x.u>>16)&1u); return (u16)(r>>16); }

__device__ __forceinline__ void gload16(const u16* g, u16* l){
  __builtin_amdgcn_global_load_lds((const __attribute__((address_space(1))) void*)g,
                                   (__attribute__((address_space(3))) void*)l, 16, 0, 0);
}

// ---------------- embedding: x = tok_emb[idx] + pos_emb (all fp32) ----------------
__global__ __launch_bounds__(256) void embed_kernel(const int* __restrict__ idx,
    const float* __restrict__ tok, const float* __restrict__ pos, float* __restrict__ x)
{
  int m = blockIdx.x;
  int t = m & (T_-1);
  int id = idx[m];
  int d = threadIdx.x*4;
  floatx4 tv = *(const floatx4*)(tok + (size_t)id*D_ + d);
  floatx4 pv = *(const floatx4*)(pos + (size_t)t*D_ + d);
  floatx4 r = tv + pv;
  *(floatx4*)(x + (size_t)m*D_ + d) = r;
}

// ---------------- fp32 -> bf16 weight conversion (2048 elems / block) ----------------
__global__ __launch_bounds__(256) void cvt_kernel(const float* __restrict__ src, u16* __restrict__ dst)
{
  size_t i = ((size_t)blockIdx.x*256 + threadIdx.x)*8;
  floatx4 a = *(const floatx4*)(src + i);
  floatx4 b = *(const floatx4*)(src + i + 4);
  short8 o;
  #pragma unroll
  for (int j=0;j<4;j++){ o[j] = (short)f2bf(a[j]); o[4+j] = (short)f2bf(b[j]); }
  *(short8*)(dst + i) = o;
}

// ---------------- layernorm: fp32 in, bf16 out ----------------
__global__ __launch_bounds__(256) void ln_kernel(const float* __restrict__ x,
    const float* __restrict__ w, const float* __restrict__ b, u16* __restrict__ out)
{
  int row = blockIdx.x, tid = threadIdx.x;
  const float* xr = x + (size_t)row*D_;
  floatx4 v = *(const floatx4*)(xr + tid*4);
  float s  = v[0]+v[1]+v[2]+v[3];
  float sq = v[0]*v[0]+v[1]*v[1]+v[2]*v[2]+v[3]*v[3];
  #pragma unroll
  for (int m=32;m>0;m>>=1){ s += __shfl_xor(s,m); sq += __shfl_xor(sq,m); }
  __shared__ float red[8];
  if ((tid&63)==0){ red[tid>>6]=s; red[4+(tid>>6)]=sq; }
  __syncthreads();
  float st  = red[0]+red[1]+red[2]+red[3];
  float sqt = red[4]+red[5]+red[6]+red[7];
  float mu = st*(1.0f/D_);
  float rs = rsqrtf(sqt*(1.0f/D_) - mu*mu + 1e-5f);
  floatx4 wv = *(const floatx4*)(w + tid*4);
  floatx4 bv = *(const floatx4*)(b + tid*4);
  u16x4 o;
  #pragma unroll
  for(int j=0;j<4;j++) o[j] = f2bf((v[j]-mu)*rs*wv[j] + bv[j]);
  *(u16x4*)(out + (size_t)row*D_ + tid*4) = o;
}

// ---------------- bf16 MFMA GEMM, double-buffered prefetch: C[M,N] = A[M,K] @ W[N,K]^T ----------------
// mode 1: fp32 store  mode 2: gelu->bf16  mode 3: fp32 +=  mode 4: bf16 store
// 1-D grid (nwg blocks), bijective XCD-chunked swizzle, y(m)-fastest within chunk.
#define BM 128
#define BN 128
#define BK 32

__global__ __launch_bounds__(256) void gemm_bf16(const u16* __restrict__ A,
    const u16* __restrict__ Bw, void* __restrict__ Cp,
    int M, int N, int K, int mode, int gy)
{
  __shared__ __align__(16) u16 As[2*BM*BK];
  __shared__ __align__(16) u16 Bs[2*BN*BK];
  int tid = threadIdx.x;

  // bijective XCD swizzle (m204): chunk the grid into 8 contiguous runs
  int bid = blockIdx.x, nwg = gridDim.x;
  int xcd = bid & 7, o8 = bid >> 3;
  int q = nwg >> 3, r = nwg & 7;
  int wg = (xcd < r ? xcd*(q+1) : r*(q+1) + (xcd-r)*q) + o8;
  int n0 = (wg / gy) * BN;   // weight panel varies slowly within an XCD chunk
  int m0 = (wg % gy) * BM;

  int w = tid>>6, lane = tid&63, quad = lane>>4, r16 = lane&15;
  int wm = (w>>1)*64, wn = (w&1)*64;

  // staging: 512 chunks of 16B per tile; wave w owns chunks [w*128, w*128+128)
  int c0 = w*128 + lane;
  int c1 = c0 + 64;
  const u16* ga0 = A  + (size_t)(m0 + (c0>>2))*K + (c0&3)*8;
  const u16* ga1 = A  + (size_t)(m0 + (c1>>2))*K + (c1&3)*8;
  const u16* gb0 = Bw + (size_t)(n0 + (c0>>2))*K + (c0&3)*8;
  const u16* gb1 = Bw + (size_t)(n0 + (c1>>2))*K + (c1&3)*8;

  floatx4 acc[4][4];
  #pragma unroll
  for(int i=0;i<4;i++)
    #pragma unroll
    for(int j=0;j<4;j++) acc[i][j] = (floatx4)0.0f;

  int nt = K/BK;
  // prologue: stage tile 0 into buffer 0
  gload16(ga0, As + w*1024);
  gload16(ga1, As + w*1024 + 512);
  gload16(gb0, Bs + w*1024);
  gload16(gb1, Bs + w*1024 + 512);
  __syncthreads();               // vmcnt(0) drained: buf0 ready

  int cur = 0;
  for (int t=0; t<nt; ++t){
    if (t+1 < nt){               // issue NEXT tile's loads before computing current
      int kn = (t+1)*BK;
      int nb = (cur^1)*(BM*BK);
      gload16(ga0 + kn, As + nb + w*1024);
      gload16(ga1 + kn, As + nb + w*1024 + 512);
      gload16(gb0 + kn, Bs + nb + w*1024);
      gload16(gb1 + kn, Bs + nb + w*1024 + 512);
    }
    const u16* Ab = As + cur*(BM*BK);
    const u16* Bb = Bs + cur*(BN*BK);
    short8 af[4], bfr[4];
    #pragma unroll
    for (int i=0;i<4;i++){
      af[i]  = *(const short8*)(Ab + (wm + i*16 + r16)*BK + quad*8);
      bfr[i] = *(const short8*)(Bb + (wn + i*16 + r16)*BK + quad*8);
    }
    #pragma unroll
    for (int mi=0;mi<4;mi++)
      #pragma unroll
      for (int ni=0;ni<4;ni++)
        acc[mi][ni] = __builtin_amdgcn_mfma_f32_16x16x32_bf16(af[mi], bfr[ni], acc[mi][ni], 0,0,0);
    __syncthreads();             // drains prefetch (vmcnt 0) + guards buffer reuse
    cur ^= 1;
  }

  #pragma unroll
  for (int mi=0;mi<4;mi++){
    #pragma unroll
    for (int ni=0;ni<4;ni++){
      #pragma unroll
      for (int r2=0;r2<4;r2++){
        int m = m0 + wm + mi*16 + quad*4 + r2;
        int n = n0 + wn + ni*16 + r16;
        float v = acc[mi][ni][r2];
        size_t off = (size_t)m*N + n;
        if (mode==1)      ((float*)Cp)[off] = v;
        else if (mode==2) ((u16*)Cp)[off]   = f2bf(0.5f*v*(1.0f + erff(v*0.70710678118654752f)));
        else if (mode==4) ((u16*)Cp)[off]   = f2bf(v);
        else              ((float*)Cp)[off] += v;
      }
    }
  }
}

// ---------------- V transpose: qkv bf16 [M][3072] -> Vt bf16 [32 bh][64 d][1024 t] ----------------
__global__ __launch_bounds__(256) void vtrans_kernel(const u16* __restrict__ qkv, u16* __restrict__ Vt)
{
  __shared__ u16 Lt[64*72];
  int bh = blockIdx.x, b = bh>>4, h = bh&15;
  int tt = blockIdx.y;
  int tid = threadIdx.x;
  #pragma unroll
  for (int cc=0; cc<2; cc++){
    int c = tid + cc*256;
    int t = c>>3, dc = (c&7)*8;
    short8 v = *(const short8*)(qkv + ((size_t)(b*T_) + tt*64 + t)*3072 + 2048 + h*64 + dc);
    *(short8*)(Lt + t*72 + dc) = v;
  }
  __syncthreads();
  #pragma unroll
  for (int cc=0; cc<2; cc++){
    int c = tid + cc*256;
    int d = c>>3, tc = (c&7)*8;
    short8 o;
    #pragma unroll
    for (int j=0;j<8;j++) o[j] = (short)Lt[(tc+j)*72 + d];
    *(short8*)(Vt + ((size_t)bh*64 + d)*T_ + tt*64 + tc) = o;
  }
}

// ---------------- MFMA flash attention ----------------
__global__ __launch_bounds__(256) void attn_mfma(const u16* __restrict__ qkv,
    const u16* __restrict__ Vt, u16* __restrict__ out)
{
  __shared__ __align__(16) u16 Qs[64*72];
  __shared__ __align__(16) u16 Ksh[64*72];
  __shared__ __align__(16) u16 Vts[64*72];
  __shared__ __align__(16) u16 Pls[4][16*72];
  int bh = blockIdx.x, b = bh>>4, h = bh&15;
  int y = blockIdx.y;
  int qt = (y<8) ? y : 23-y;                 // work-balance pairing: qt(y)+qt(y+8)=15
  int tid = threadIdx.x, w = tid>>6, lane = tid&63, quad = lane>>4, r16 = lane&15;

  #pragma unroll
  for (int cc=0; cc<2; cc++){
    int c = tid + cc*256;
    int r = c>>3, dc = (c&7)*8;
    short8 v = *(const short8*)(qkv + ((size_t)(b*T_) + qt*64 + r)*3072 + h*64 + dc);
    *(short8*)(Qs + r*72 + dc) = v;
  }
  __syncthreads();
  short8 qf[2];
  qf[0] = *(const short8*)(Qs + (w*16 + r16)*72 + quad*8);
  qf[1] = *(const short8*)(Qs + (w*16 + r16)*72 + quad*8 + 32);

  floatx4 oacc[4];
  #pragma unroll
  for (int i=0;i<4;i++) oacc[i] = (floatx4)0.0f;
  float m_run[4], l_run[4];
  #pragma unroll
  for (int r=0;r<4;r++){ m_run[r] = -INFINITY; l_run[r] = 0.f; }
  int qg = qt*64 + w*16 + quad*4;

  for (int kb=0; kb<=qt; kb++){
    __syncthreads();
    #pragma unroll
    for (int cc=0; cc<2; cc++){
      int c = tid + cc*256;
      int r = c>>3, dc = (c&7)*8;
      short8 kv = *(const short8*)(qkv + ((size_t)(b*T_) + kb*64 + r)*3072 + D_ + h*64 + dc);
      *(short8*)(Ksh + r*72 + dc) = kv;
      short8 vv = *(const short8*)(Vt + ((size_t)bh*64 + r)*T_ + kb*64 + dc);
      *(short8*)(Vts + r*72 + dc) = vv;
    }
    __syncthreads();

    floatx4 sa[4];
    #pragma unroll
    for (int nt=0;nt<4;nt++) sa[nt] = (floatx4)0.0f;
    #pragma unroll
    for (int nt=0;nt<4;nt++){
      short8 kf0 = *(const short8*)(Ksh + (nt*16 + r16)*72 + quad*8);
      short8 kf1 = *(const short8*)(Ksh + (nt*16 + r16)*72 + quad*8 + 32);
      sa[nt] = __builtin_amdgcn_mfma_f32_16x16x32_bf16(qf[0], kf0, sa[nt], 0,0,0);
      sa[nt] = __builtin_amdgcn_mfma_f32_16x16x32_bf16(qf[1], kf1, sa[nt], 0,0,0);
    }
    bool diag = (kb==qt);
    #pragma unroll
    for (int nt=0;nt<4;nt++)
      #pragma unroll
      for (int r=0;r<4;r++){
        float s = sa[nt][r]*0.125f;
        if (diag && (kb*64 + nt*16 + r16) > (qg + r)) s = -INFINITY;
        sa[nt][r] = s;
      }

    float mt[4];
    #pragma unroll
    for (int r=0;r<4;r++) mt[r] = fmaxf(fmaxf(sa[0][r],sa[1][r]), fmaxf(sa[2][r],sa[3][r]));
    #pragma unroll
    for (int msk=1; msk<16; msk<<=1)
      #pragma unroll
      for (int r=0;r<4;r++) mt[r] = fmaxf(mt[r], __shfl_xor(mt[r], msk));
    float alpha[4];
    #pragma unroll
    for (int r=0;r<4;r++){
      float nm = fmaxf(m_run[r], mt[r]);
      alpha[r] = __expf(m_run[r]-nm);
      m_run[r] = nm;
    }
    float psum[4] = {0.f,0.f,0.f,0.f};
    #pragma unroll
    for (int nt=0;nt<4;nt++)
      #pragma unroll
      for (int r=0;r<4;r++){
        float p = __expf(sa[nt][r]-m_run[r]);
        sa[nt][r] = p;
        psum[r] += p;
      }
    #pragma unroll
    for (int msk=1; msk<16; msk<<=1)
      #pragma unroll
      for (int r=0;r<4;r++) psum[r] += __shfl_xor(psum[r], msk);
    #pragma unroll
    for (int r=0;r<4;r++) l_run[r] = l_run[r]*alpha[r] + psum[r];
    #pragma unroll
    for (int nt=0;nt<4;nt++)
      #pragma unroll
      for (int r=0;r<4;r++) oacc[nt][r] *= alpha[r];

    #pragma unroll
    for (int nt=0;nt<4;nt++)
      #pragma unroll
      for (int r=0;r<4;r++)
        Pls[w][(quad*4+r)*72 + nt*16 + r16] = f2bf(sa[nt][r]);
    short8 pf0 = *(const short8*)(&Pls[w][r16*72 + quad*8]);
    short8 pf1 = *(const short8*)(&Pls[w][r16*72 + quad*8 + 32]);

    #pragma unroll
    for (int nt=0;nt<4;nt++){
      short8 vf0 = *(const short8*)(Vts + (nt*16 + r16)*72 + quad*8);
      short8 vf1 = *(const short8*)(Vts + (nt*16 + r16)*72 + quad*8 + 32);
      oacc[nt] = __builtin_amdgcn_mfma_f32_16x16x32_bf16(pf0, vf0, oacc[nt], 0,0,0);
      oacc[nt] = __builtin_amdgcn_mfma_f32_16x16x32_bf16(pf1, vf1, oacc[nt], 0,0,0);
    }
  }

  float inv[4];
  #pragma unroll
  for (int r=0;r<4;r++) inv[r] = 1.f/l_run[r];
  #pragma unroll
  for (int nt=0;nt<4;nt++)
    #pragma unroll
    for (int r=0;r<4;r++)
      out[((size_t)(b*T_) + qt*64 + w*16 + quad*4 + r)*D_ + h*64 + nt*16 + r16] = f2bf(oacc[nt][r]*inv[r]);
}

// ---------------- driver ----------------
extern "C" void kernel_launch(void* const* d_in, const int* in_sizes, int n_in,
                              void* d_out, int out_size, void* d_ws, size_t ws_size,
                              hipStream_t stream)
{
  const int*   idx = (const int*)d_in[0];
  const float* tok = (const float*)d_in[1];
  const float* pos = (const float*)d_in[2];
  const float* ln1w = (const float*)d_in[3];
  const float* ln1b = (const float*)d_in[4];
  const float* qkvw = (const float*)d_in[5];
  const float* outw = (const float*)d_in[6];
  const float* ln2w = (const float*)d_in[7];
  const float* ln2b = (const float*)d_in[8];
  const float* f1w  = (const float*)d_in[9];
  const float* f2w  = (const float*)d_in[10];
  const float* lnfw = (const float*)d_in[11];
  const float* lnfb = (const float*)d_in[12];

  char* ws = (char*)d_ws;
  float* x   = (float*)ws;                      // 8 MB   [2048,1024] fp32 residual
  u16*  h    = (u16*) (ws + (size_t)( 8<<20));  // 4 MB   [2048,1024] bf16 LN out
  u16*  qkv  = (u16*) (ws + (size_t)(12<<20));  // 12 MB  [2048,3072] bf16
  u16*  ao   = (u16*) (ws + (size_t)(24<<20));  // 4 MB   [2048,1024] bf16 attn out
  u16*  ff   = (u16*) (ws + (size_t)(28<<20));  // 16 MB  [2048,4096] bf16 gelu out
  u16*  vt   = (u16*) (ws + (size_t)(44<<20));  // 4 MB   [32,64,1024] bf16 V^T
  u16*  wb   = (u16*) (ws + (size_t)(48<<20));  // 64 MB  bf16 weight scratch
  if (ws_size < ((size_t)120<<20)) return;

  const int GY = M_/BM;   // 16
  embed_kernel<<<M_, 256, 0, stream>>>(idx, tok, pos, x);
  for (int l=0; l<L_; l++){
    ln_kernel<<<M_, 256, 0, stream>>>(x, ln1w + l*D_, ln1b + l*D_, h);
    cvt_kernel<<<(3*D_*D_)/2048, 256, 0, stream>>>(qkvw + (size_t)l*3*D_*D_, wb);
    gemm_bf16<<<(3*D_/BN)*GY, 256, 0, stream>>>(h, wb, qkv, M_, 3*D_, D_, 4, GY);
    vtrans_kernel<<<dim3(B_*H_, T_/64), 256, 0, stream>>>(qkv, vt);
    attn_mfma<<<dim3(B_*H_, T_/64), 256, 0, stream>>>(qkv, vt, ao);
    cvt_kernel<<<(D_*D_)/2048, 256, 0, stream>>>(outw + (size_t)l*D_*D_, wb);
    gemm_bf16<<<(D_/BN)*GY, 256, 0, stream>>>(ao, wb, x, M_, D_, D_, 3, GY);
    ln_kernel<<<M_, 256, 0, stream>>>(x, ln2w + l*D_, ln2b + l*D_, h);
    cvt_kernel<<<(DFF_*D_)/2048, 256, 0, stream>>>(f1w + (size_t)l*DFF_*D_, wb);
    gemm_bf16<<<(DFF_/BN)*GY, 256, 0, stream>>>(h, wb, ff, M_, DFF_, D_, 2, GY);
    cvt_kernel<<<(D_*DFF_)/2048, 256, 0, stream>>>(f2w + (size_t)l*D_*DFF_, wb);
    gemm_bf16<<<(D_/BN)*GY, 256, 0, stream>>>(ff, wb, x, M_, D_, DFF_, 3, GY);
  }
  ln_kernel<<<M_, 256, 0, stream>>>(x, lnfw, lnfb, h);
  cvt_kernel<<<(V_*D_)/2048, 256, 0, stream>>>(tok, wb);
  gemm_bf16<<<(V_/BN)*GY, 256, 0, stream>>>(h, wb, (float*)d_out, M_, V_, D_, 1, GY);
}

// Round 6
// 1978.164 us; speedup vs baseline: 2.2968x; 1.1871x over previous
//
#include <hip/hip_runtime.h>
#include <math.h>

typedef unsigned short u16;
typedef short short8 __attribute__((ext_vector_type(8)));
typedef float floatx4 __attribute__((ext_vector_type(4)));
typedef u16 u16x4 __attribute__((ext_vector_type(4)));

#define L_ 6
#define D_ 1024
#define DFF_ 4096
#define V_ 32000
#define T_ 1024
#define B_ 2
#define H_ 16
#define M_ (B_*T_)

__device__ __forceinline__ float b2f(u16 v){ union{unsigned u; float f;} x; x.u = ((unsigned)v)<<16; return x.f; }
__device__ __forceinline__ u16 f2bf(float f){ union{float f; unsigned u;} x; x.f=f; unsigned r = x.u + 0x7fffu + ((x.u>>16)&1u); return (u16)(r>>16); }

__device__ __forceinline__ void gload16(const u16* g, u16* l){
  __builtin_amdgcn_global_load_lds((const __attribute__((address_space(1))) void*)g,
                                   (__attribute__((address_space(3))) void*)l, 16, 0, 0);
}

// ---------------- embedding: x = tok_emb[idx] + pos_emb (all fp32) ----------------
__global__ __launch_bounds__(256) void embed_kernel(const int* __restrict__ idx,
    const float* __restrict__ tok, const float* __restrict__ pos, float* __restrict__ x)
{
  int m = blockIdx.x;
  int t = m & (T_-1);
  int id = idx[m];
  int d = threadIdx.x*4;
  floatx4 tv = *(const floatx4*)(tok + (size_t)id*D_ + d);
  floatx4 pv = *(const floatx4*)(pos + (size_t)t*D_ + d);
  floatx4 r = tv + pv;
  *(floatx4*)(x + (size_t)m*D_ + d) = r;
}

// ---------------- fp32 -> bf16 weight conversion (2048 elems / block) ----------------
__global__ __launch_bounds__(256) void cvt_kernel(const float* __restrict__ src, u16* __restrict__ dst)
{
  size_t i = ((size_t)blockIdx.x*256 + threadIdx.x)*8;
  floatx4 a = *(const floatx4*)(src + i);
  floatx4 b = *(const floatx4*)(src + i + 4);
  short8 o;
  #pragma unroll
  for (int j=0;j<4;j++){ o[j] = (short)f2bf(a[j]); o[4+j] = (short)f2bf(b[j]); }
  *(short8*)(dst + i) = o;
}

// ---------------- layernorm: fp32 in, bf16 out ----------------
__global__ __launch_bounds__(256) void ln_kernel(const float* __restrict__ x,
    const float* __restrict__ w, const float* __restrict__ b, u16* __restrict__ out)
{
  int row = blockIdx.x, tid = threadIdx.x;
  const float* xr = x + (size_t)row*D_;
  floatx4 v = *(const floatx4*)(xr + tid*4);
  float s  = v[0]+v[1]+v[2]+v[3];
  float sq = v[0]*v[0]+v[1]*v[1]+v[2]*v[2]+v[3]*v[3];
  #pragma unroll
  for (int m=32;m>0;m>>=1){ s += __shfl_xor(s,m); sq += __shfl_xor(sq,m); }
  __shared__ float red[8];
  if ((tid&63)==0){ red[tid>>6]=s; red[4+(tid>>6)]=sq; }
  __syncthreads();
  float st  = red[0]+red[1]+red[2]+red[3];
  float sqt = red[4]+red[5]+red[6]+red[7];
  float mu = st*(1.0f/D_);
  float rs = rsqrtf(sqt*(1.0f/D_) - mu*mu + 1e-5f);
  floatx4 wv = *(const floatx4*)(w + tid*4);
  floatx4 bv = *(const floatx4*)(b + tid*4);
  u16x4 o;
  #pragma unroll
  for(int j=0;j<4;j++) o[j] = f2bf((v[j]-mu)*rs*wv[j] + bv[j]);
  *(u16x4*)(out + (size_t)row*D_ + tid*4) = o;
}

// ---------------- bf16 MFMA GEMM, dbuf prefetch + swizzled LDS + optional split-K ----------------
// C[M,N] = A[M,K] @ W[N,K]^T
// mode 1: fp32 store  mode 2: gelu->bf16  mode 3: fp32 atomic +=  mode 4: bf16 store
// LDS slot swizzle (both-sides, rule #21): tile row r (64B = 4x16B slots), LDS slot s_lds
// holds global slot s_lds ^ ((r>>1)&3). Staging permutes the GLOBAL source address
// (LDS write stays linear for global_load_lds); frag ds_read applies the same XOR.
// -> every aligned 8-lane read phase covers all 8 bank groups: conflict-free.
#define BM 128
#define BN 128
#define BK 32

__global__ __launch_bounds__(256) void gemm_bf16(const u16* __restrict__ A,
    const u16* __restrict__ Bw, void* __restrict__ Cp,
    int M, int N, int K, int mode, int gy, int sk)
{
  __shared__ __align__(16) u16 As[2*BM*BK];
  __shared__ __align__(16) u16 Bs[2*BN*BK];
  int tid = threadIdx.x;

  // bijective XCD swizzle (m204): chunk the grid into 8 contiguous runs
  int bid = blockIdx.x, nwg = gridDim.x;
  int xcd = bid & 7, o8 = bid >> 3;
  int q = nwg >> 3, r = nwg & 7;
  int wg = (xcd < r ? xcd*(q+1) : r*(q+1) + (xcd-r)*q) + o8;
  int body = nwg / sk;               // blocks per K-split
  int s    = wg / body;              // which K-split
  int rem  = wg % body;
  int n0 = (rem / gy) * BN;          // weight panel varies slowly within an XCD chunk
  int m0 = (rem % gy) * BM;
  int Ks   = K / sk;                 // K-extent of this split
  int kb0  = s * Ks;                 // starting k

  int w = tid>>6, lane = tid&63, quad = lane>>4, r16 = lane&15;
  int wm = (w>>1)*64, wn = (w&1)*64;

  // staging: chunk p -> tile row r=p>>2, LDS slot p&3; global slot = (p&3) ^ ((r>>1)&3)
  int c0 = w*128 + lane;
  int c1 = c0 + 64;
  int r0 = c0>>2, r1 = c1>>2;
  int sg0 = (c0&3) ^ ((r0>>1)&3);
  int sg1 = (c1&3) ^ ((r1>>1)&3);
  const u16* ga0 = A  + (size_t)(m0 + r0)*K + kb0 + sg0*8;
  const u16* ga1 = A  + (size_t)(m0 + r1)*K + kb0 + sg1*8;
  const u16* gb0 = Bw + (size_t)(n0 + r0)*K + kb0 + sg0*8;
  const u16* gb1 = Bw + (size_t)(n0 + r1)*K + kb0 + sg1*8;

  floatx4 acc[4][4];
  #pragma unroll
  for(int i=0;i<4;i++)
    #pragma unroll
    for(int j=0;j<4;j++) acc[i][j] = (floatx4)0.0f;

  int ntk = Ks/BK;
  // prologue: stage tile 0 into buffer 0
  gload16(ga0, As + w*1024);
  gload16(ga1, As + w*1024 + 512);
  gload16(gb0, Bs + w*1024);
  gload16(gb1, Bs + w*1024 + 512);
  __syncthreads();               // vmcnt(0) drained: buf0 ready

  // fragment swizzle: slot = quad ^ ((r16>>1)&3)  (uniform across i and wm)
  int sl = (quad ^ ((r16>>1)&3))*8;
  int cur = 0;
  for (int t=0; t<ntk; ++t){
    if (t+1 < ntk){              // issue NEXT tile's loads before computing current
      int kn = (t+1)*BK;
      int nb = (cur^1)*(BM*BK);
      gload16(ga0 + kn, As + nb + w*1024);
      gload16(ga1 + kn, As + nb + w*1024 + 512);
      gload16(gb0 + kn, Bs + nb + w*1024);
      gload16(gb1 + kn, Bs + nb + w*1024 + 512);
    }
    const u16* Ab = As + cur*(BM*BK);
    const u16* Bb = Bs + cur*(BN*BK);
    short8 af[4], bfr[4];
    #pragma unroll
    for (int i=0;i<4;i++){
      af[i]  = *(const short8*)(Ab + (wm + i*16 + r16)*BK + sl);
      bfr[i] = *(const short8*)(Bb + (wn + i*16 + r16)*BK + sl);
    }
    #pragma unroll
    for (int mi=0;mi<4;mi++)
      #pragma unroll
      for (int ni=0;ni<4;ni++)
        acc[mi][ni] = __builtin_amdgcn_mfma_f32_16x16x32_bf16(af[mi], bfr[ni], acc[mi][ni], 0,0,0);
    __syncthreads();             // drains prefetch (vmcnt 0) + guards buffer reuse
    cur ^= 1;
  }

  #pragma unroll
  for (int mi=0;mi<4;mi++){
    #pragma unroll
    for (int ni=0;ni<4;ni++){
      #pragma unroll
      for (int r2=0;r2<4;r2++){
        int m = m0 + wm + mi*16 + quad*4 + r2;
        int n = n0 + wn + ni*16 + r16;
        float v = acc[mi][ni][r2];
        size_t off = (size_t)m*N + n;
        if (mode==1)      ((float*)Cp)[off] = v;
        else if (mode==2) ((u16*)Cp)[off]   = f2bf(0.5f*v*(1.0f + erff(v*0.70710678118654752f)));
        else if (mode==4) ((u16*)Cp)[off]   = f2bf(v);
        else              atomicAdd((float*)Cp + off, v);   // split-K safe
      }
    }
  }
}

// ---------------- V transpose: qkv bf16 [M][3072] -> Vt bf16 [32 bh][64 d][1024 t] ----------------
__global__ __launch_bounds__(256) void vtrans_kernel(const u16* __restrict__ qkv, u16* __restrict__ Vt)
{
  __shared__ u16 Lt[64*72];
  int bh = blockIdx.x, b = bh>>4, h = bh&15;
  int tt = blockIdx.y;
  int tid = threadIdx.x;
  #pragma unroll
  for (int cc=0; cc<2; cc++){
    int c = tid + cc*256;
    int t = c>>3, dc = (c&7)*8;
    short8 v = *(const short8*)(qkv + ((size_t)(b*T_) + tt*64 + t)*3072 + 2048 + h*64 + dc);
    *(short8*)(Lt + t*72 + dc) = v;
  }
  __syncthreads();
  #pragma unroll
  for (int cc=0; cc<2; cc++){
    int c = tid + cc*256;
    int d = c>>3, tc = (c&7)*8;
    short8 o;
    #pragma unroll
    for (int j=0;j<8;j++) o[j] = (short)Lt[(tc+j)*72 + d];
    *(short8*)(Vt + ((size_t)bh*64 + d)*T_ + tt*64 + tc) = o;
  }
}

// ---------------- MFMA flash attention ----------------
__global__ __launch_bounds__(256) void attn_mfma(const u16* __restrict__ qkv,
    const u16* __restrict__ Vt, u16* __restrict__ out)
{
  __shared__ __align__(16) u16 Qs[64*72];
  __shared__ __align__(16) u16 Ksh[64*72];
  __shared__ __align__(16) u16 Vts[64*72];
  __shared__ __align__(16) u16 Pls[4][16*72];
  int bh = blockIdx.x, b = bh>>4, h = bh&15;
  int y = blockIdx.y;
  int qt = (y<8) ? y : 23-y;                 // work-balance pairing: qt(y)+qt(y+8)=15
  int tid = threadIdx.x, w = tid>>6, lane = tid&63, quad = lane>>4, r16 = lane&15;

  #pragma unroll
  for (int cc=0; cc<2; cc++){
    int c = tid + cc*256;
    int r = c>>3, dc = (c&7)*8;
    short8 v = *(const short8*)(qkv + ((size_t)(b*T_) + qt*64 + r)*3072 + h*64 + dc);
    *(short8*)(Qs + r*72 + dc) = v;
  }
  __syncthreads();
  short8 qf[2];
  qf[0] = *(const short8*)(Qs + (w*16 + r16)*72 + quad*8);
  qf[1] = *(const short8*)(Qs + (w*16 + r16)*72 + quad*8 + 32);

  floatx4 oacc[4];
  #pragma unroll
  for (int i=0;i<4;i++) oacc[i] = (floatx4)0.0f;
  float m_run[4], l_run[4];
  #pragma unroll
  for (int r=0;r<4;r++){ m_run[r] = -INFINITY; l_run[r] = 0.f; }
  int qg = qt*64 + w*16 + quad*4;

  for (int kb=0; kb<=qt; kb++){
    __syncthreads();
    #pragma unroll
    for (int cc=0; cc<2; cc++){
      int c = tid + cc*256;
      int r = c>>3, dc = (c&7)*8;
      short8 kv = *(const short8*)(qkv + ((size_t)(b*T_) + kb*64 + r)*3072 + D_ + h*64 + dc);
      *(short8*)(Ksh + r*72 + dc) = kv;
      short8 vv = *(const short8*)(Vt + ((size_t)bh*64 + r)*T_ + kb*64 + dc);
      *(short8*)(Vts + r*72 + dc) = vv;
    }
    __syncthreads();

    floatx4 sa[4];
    #pragma unroll
    for (int nt=0;nt<4;nt++) sa[nt] = (floatx4)0.0f;
    #pragma unroll
    for (int nt=0;nt<4;nt++){
      short8 kf0 = *(const short8*)(Ksh + (nt*16 + r16)*72 + quad*8);
      short8 kf1 = *(const short8*)(Ksh + (nt*16 + r16)*72 + quad*8 + 32);
      sa[nt] = __builtin_amdgcn_mfma_f32_16x16x32_bf16(qf[0], kf0, sa[nt], 0,0,0);
      sa[nt] = __builtin_amdgcn_mfma_f32_16x16x32_bf16(qf[1], kf1, sa[nt], 0,0,0);
    }
    bool diag = (kb==qt);
    #pragma unroll
    for (int nt=0;nt<4;nt++)
      #pragma unroll
      for (int r=0;r<4;r++){
        float s = sa[nt][r]*0.125f;
        if (diag && (kb*64 + nt*16 + r16) > (qg + r)) s = -INFINITY;
        sa[nt][r] = s;
      }

    float mt[4];
    #pragma unroll
    for (int r=0;r<4;r++) mt[r] = fmaxf(fmaxf(sa[0][r],sa[1][r]), fmaxf(sa[2][r],sa[3][r]));
    #pragma unroll
    for (int msk=1; msk<16; msk<<=1)
      #pragma unroll
      for (int r=0;r<4;r++) mt[r] = fmaxf(mt[r], __shfl_xor(mt[r], msk));
    float alpha[4];
    #pragma unroll
    for (int r=0;r<4;r++){
      float nm = fmaxf(m_run[r], mt[r]);
      alpha[r] = __expf(m_run[r]-nm);
      m_run[r] = nm;
    }
    float psum[4] = {0.f,0.f,0.f,0.f};
    #pragma unroll
    for (int nt=0;nt<4;nt++)
      #pragma unroll
      for (int r=0;r<4;r++){
        float p = __expf(sa[nt][r]-m_run[r]);
        sa[nt][r] = p;
        psum[r] += p;
      }
    #pragma unroll
    for (int msk=1; msk<16; msk<<=1)
      #pragma unroll
      for (int r=0;r<4;r++) psum[r] += __shfl_xor(psum[r], msk);
    #pragma unroll
    for (int r=0;r<4;r++) l_run[r] = l_run[r]*alpha[r] + psum[r];
    #pragma unroll
    for (int nt=0;nt<4;nt++)
      #pragma unroll
      for (int r=0;r<4;r++) oacc[nt][r] *= alpha[r];

    #pragma unroll
    for (int nt=0;nt<4;nt++)
      #pragma unroll
      for (int r=0;r<4;r++)
        Pls[w][(quad*4+r)*72 + nt*16 + r16] = f2bf(sa[nt][r]);
    short8 pf0 = *(const short8*)(&Pls[w][r16*72 + quad*8]);
    short8 pf1 = *(const short8*)(&Pls[w][r16*72 + quad*8 + 32]);

    #pragma unroll
    for (int nt=0;nt<4;nt++){
      short8 vf0 = *(const short8*)(Vts + (nt*16 + r16)*72 + quad*8);
      short8 vf1 = *(const short8*)(Vts + (nt*16 + r16)*72 + quad*8 + 32);
      oacc[nt] = __builtin_amdgcn_mfma_f32_16x16x32_bf16(pf0, vf0, oacc[nt], 0,0,0);
      oacc[nt] = __builtin_amdgcn_mfma_f32_16x16x32_bf16(pf1, vf1, oacc[nt], 0,0,0);
    }
  }

  float inv[4];
  #pragma unroll
  for (int r=0;r<4;r++) inv[r] = 1.f/l_run[r];
  #pragma unroll
  for (int nt=0;nt<4;nt++)
    #pragma unroll
    for (int r=0;r<4;r++)
      out[((size_t)(b*T_) + qt*64 + w*16 + quad*4 + r)*D_ + h*64 + nt*16 + r16] = f2bf(oacc[nt][r]*inv[r]);
}

// ---------------- driver ----------------
extern "C" void kernel_launch(void* const* d_in, const int* in_sizes, int n_in,
                              void* d_out, int out_size, void* d_ws, size_t ws_size,
                              hipStream_t stream)
{
  const int*   idx = (const int*)d_in[0];
  const float* tok = (const float*)d_in[1];
  const float* pos = (const float*)d_in[2];
  const float* ln1w = (const float*)d_in[3];
  const float* ln1b = (const float*)d_in[4];
  const float* qkvw = (const float*)d_in[5];
  const float* outw = (const float*)d_in[6];
  const float* ln2w = (const float*)d_in[7];
  const float* ln2b = (const float*)d_in[8];
  const float* f1w  = (const float*)d_in[9];
  const float* f2w  = (const float*)d_in[10];
  const float* lnfw = (const float*)d_in[11];
  const float* lnfb = (const float*)d_in[12];

  char* ws = (char*)d_ws;
  float* x   = (float*)ws;                      // 8 MB   [2048,1024] fp32 residual
  u16*  h    = (u16*) (ws + (size_t)( 8<<20));  // 4 MB   [2048,1024] bf16 LN out
  u16*  qkv  = (u16*) (ws + (size_t)(12<<20));  // 12 MB  [2048,3072] bf16
  u16*  ao   = (u16*) (ws + (size_t)(24<<20));  // 4 MB   [2048,1024] bf16 attn out
  u16*  ff   = (u16*) (ws + (size_t)(28<<20));  // 16 MB  [2048,4096] bf16 gelu out
  u16*  vt   = (u16*) (ws + (size_t)(44<<20));  // 4 MB   [32,64,1024] bf16 V^T
  u16*  wb   = (u16*) (ws + (size_t)(48<<20));  // 64 MB  bf16 weight scratch
  if (ws_size < ((size_t)120<<20)) return;

  const int GY = M_/BM;   // 16
  embed_kernel<<<M_, 256, 0, stream>>>(idx, tok, pos, x);
  for (int l=0; l<L_; l++){
    ln_kernel<<<M_, 256, 0, stream>>>(x, ln1w + l*D_, ln1b + l*D_, h);
    cvt_kernel<<<(3*D_*D_)/2048, 256, 0, stream>>>(qkvw + (size_t)l*3*D_*D_, wb);
    gemm_bf16<<<(3*D_/BN)*GY, 256, 0, stream>>>(h, wb, qkv, M_, 3*D_, D_, 4, GY, 1);
    vtrans_kernel<<<dim3(B_*H_, T_/64), 256, 0, stream>>>(qkv, vt);
    attn_mfma<<<dim3(B_*H_, T_/64), 256, 0, stream>>>(qkv, vt, ao);
    cvt_kernel<<<(D_*D_)/2048, 256, 0, stream>>>(outw + (size_t)l*D_*D_, wb);
    gemm_bf16<<<(D_/BN)*GY*2, 256, 0, stream>>>(ao, wb, x, M_, D_, D_, 3, GY, 2);      // split-K=2
    ln_kernel<<<M_, 256, 0, stream>>>(x, ln2w + l*D_, ln2b + l*D_, h);
    cvt_kernel<<<(DFF_*D_)/2048, 256, 0, stream>>>(f1w + (size_t)l*DFF_*D_, wb);
    gemm_bf16<<<(DFF_/BN)*GY, 256, 0, stream>>>(h, wb, ff, M_, DFF_, D_, 2, GY, 1);
    cvt_kernel<<<(D_*DFF_)/2048, 256, 0, stream>>>(f2w + (size_t)l*D_*DFF_, wb);
    gemm_bf16<<<(D_/BN)*GY*4, 256, 0, stream>>>(ff, wb, x, M_, D_, DFF_, 3, GY, 4);    // split-K=4
  }
  ln_kernel<<<M_, 256, 0, stream>>>(x, lnfw, lnfb, h);
  cvt_kernel<<<(V_*D_)/2048, 256, 0, stream>>>(tok, wb);
  gemm_bf16<<<(V_/BN)*GY, 256, 0, stream>>>(h, wb, (float*)d_out, M_, V_, D_, 1, GY, 1);
}